// Round 1
// baseline (706.965 us; speedup 1.0000x reference)
//
#include <hip/hip_runtime.h>
#include <math.h>

#define N_TOK   65536
#define DIM     128
#define KCODE   1024

// ---- d_out element offsets ----
// [0]                  e_latent_loss
// [1 .. 8388608]       quantized_st (65536 x 128)
// [8388609]            perplexity
// [8388610 ..]         encodings (65536 x 1024)
#define OUT_QUANT_OFF 1
#define OUT_PERP_OFF  8388609
#define OUT_ENC_OFF   8388610

// ---- workspace byte offsets ----
#define WS_SE64     0            // 1024 * 8
#define WS_SE32     8192         // 1024 * 4
#define WS_IDX      12288        // 65536 * 4
#define WS_FLAGLIST 274432       // 65536 * 4
#define WS_FLAGCNT  536576       // 4
#define WS_HIST     536704       // 1024 * 4
#define WS_PART     540800       // 32768 * 8  -> ends 802944

#define MARGIN 1e-5f

// ---------------------------------------------------------------------------
// Prep: per-code squared norms in f64 (refine) and f32 (main pass)
// ---------------------------------------------------------------------------
__global__ __launch_bounds__(256) void k_prep(const float* __restrict__ emb,
                                              double* __restrict__ se64,
                                              float* __restrict__ se32) {
    int k = blockIdx.x * 256 + threadIdx.x;
    if (k >= KCODE) return;
    const float4* row = reinterpret_cast<const float4*>(emb + (size_t)k * DIM);
    double s = 0.0;
    for (int i = 0; i < DIM / 4; ++i) {
        float4 v = row[i];
        s += (double)v.x * v.x + (double)v.y * v.y + (double)v.z * v.z + (double)v.w * v.w;
    }
    se64[k] = s;
    se32[k] = (float)s;
}

// ---------------------------------------------------------------------------
// Main distance/argmin pass.
// Block: 256 threads. Tile: 64 tokens x (16 chunks of 64 codes).
// Thread (tx=tid&15, ty=tid>>4) owns 4 tokens {ty+16i} x 4 codes {tx+16j}.
// LDS tiles stored row-stride 128 with XOR swizzle  d ^ ((row&7)<<2)
// -> b128-aligned, conflict-free compute reads, 64 KB total.
// ---------------------------------------------------------------------------
__global__ __launch_bounds__(256, 2) void k_main(const float* __restrict__ xg,
                                                 const float* __restrict__ emb,
                                                 const float* __restrict__ se32,
                                                 int* __restrict__ idx,
                                                 int* __restrict__ flaglist,
                                                 int* __restrict__ flagcnt) {
    __shared__ float xs[64 * 128];
    __shared__ float es[64 * 128];

    const int tid = threadIdx.x;
    const int tx = tid & 15;
    const int ty = tid >> 4;
    const int tok0 = blockIdx.x * 64;

    // stage x tile (64 rows x 128 floats), swizzled
    for (int it = 0; it < 8; ++it) {
        int flat = (it << 8) + tid;          // 0..2047
        int t = flat >> 5;                   // local token 0..63
        int d4 = flat & 31;                  // float4 column
        float4 v = reinterpret_cast<const float4*>(xg + ((size_t)(tok0 + t) << 7))[d4];
        int w = (t << 7) + ((d4 << 2) ^ ((t & 7) << 2));
        *reinterpret_cast<float4*>(&xs[w]) = v;
    }

    float v1[4], v2[4];
    int i1[4];
#pragma unroll
    for (int i = 0; i < 4; ++i) { v1[i] = 3.0e38f; v2[i] = 3.0e38f; i1[i] = 0; }

    const int xsw = (ty & 7) << 2;
    const int esw = (tx & 7) << 2;

    for (int ch = 0; ch < 16; ++ch) {
        __syncthreads();   // previous chunk's readers done before restaging
        for (int it = 0; it < 8; ++it) {
            int flat = (it << 8) + tid;
            int c = flat >> 5;
            int d4 = flat & 31;
            float4 v = reinterpret_cast<const float4*>(emb + ((size_t)((ch << 6) + c) << 7))[d4];
            int w = (c << 7) + ((d4 << 2) ^ ((c & 7) << 2));
            *reinterpret_cast<float4*>(&es[w]) = v;
        }
        __syncthreads();

        float acc[4][4];
#pragma unroll
        for (int i = 0; i < 4; ++i)
#pragma unroll
            for (int j = 0; j < 4; ++j) acc[i][j] = 0.0f;

        for (int d0 = 0; d0 < 128; d0 += 4) {
            const int xo = d0 ^ xsw;
            const int eo = d0 ^ esw;
            float4 xa[4], eb[4];
#pragma unroll
            for (int i = 0; i < 4; ++i)
                xa[i] = *reinterpret_cast<const float4*>(&xs[((ty + (i << 4)) << 7) + xo]);
#pragma unroll
            for (int j = 0; j < 4; ++j)
                eb[j] = *reinterpret_cast<const float4*>(&es[((tx + (j << 4)) << 7) + eo]);
#pragma unroll
            for (int i = 0; i < 4; ++i)
#pragma unroll
                for (int j = 0; j < 4; ++j) {
                    acc[i][j] = fmaf(xa[i].x, eb[j].x, acc[i][j]);
                    acc[i][j] = fmaf(xa[i].y, eb[j].y, acc[i][j]);
                    acc[i][j] = fmaf(xa[i].z, eb[j].z, acc[i][j]);
                    acc[i][j] = fmaf(xa[i].w, eb[j].w, acc[i][j]);
                }
        }

        // finalize chunk: u = ||e||^2 - 2 x.e   (||x||^2 constant per token)
#pragma unroll
        for (int j = 0; j < 4; ++j) {
            int c = (ch << 6) + tx + (j << 4);     // ascending across ch, j
            float se_c = se32[c];
#pragma unroll
            for (int i = 0; i < 4; ++i) {
                float u = fmaf(-2.0f, acc[i][j], se_c);
                if (u < v1[i]) { v2[i] = v1[i]; v1[i] = u; i1[i] = c; }
                else if (u < v2[i]) v2[i] = u;
            }
        }
    }

    // cross-thread reduction: 16 partials per token. Reuse es as scratch.
    __syncthreads();
    float* rv1 = es;
    float* rv2 = es + 1024;
    int* ri1 = reinterpret_cast<int*>(es + 2048);
#pragma unroll
    for (int i = 0; i < 4; ++i) {
        int slot = ((ty + (i << 4)) << 4) + tx;    // token*16 + tx
        rv1[slot] = v1[i];
        rv2[slot] = v2[i];
        ri1[slot] = i1[i];
    }
    __syncthreads();

    if (tid < 64) {
        int base = tid << 4;
        float V1 = rv1[base], V2 = rv2[base];
        int I = ri1[base];
        for (int s = 1; s < 16; ++s) {
            float b1 = rv1[base + s];
            float b2 = rv2[base + s];
            int bi = ri1[base + s];
            if (b1 < V1 || (b1 == V1 && bi < I)) { V2 = fminf(V1, b2); V1 = b1; I = bi; }
            else { V2 = fminf(V2, b1); }
        }
        idx[tok0 + tid] = I;
        if (V2 - V1 < MARGIN) {
            int p = atomicAdd(flagcnt, 1);
            flaglist[p] = tok0 + tid;
        }
    }
}

// ---------------------------------------------------------------------------
// fp64 full rescan for near-tie tokens (~0.3% expected)
// ---------------------------------------------------------------------------
__global__ __launch_bounds__(256) void k_refine(const float* __restrict__ xg,
                                                const float* __restrict__ emb,
                                                const double* __restrict__ se64,
                                                const int* __restrict__ flaglist,
                                                const int* __restrict__ flagcnt,
                                                int* __restrict__ idx) {
    __shared__ float xsh[DIM];
    __shared__ double rv[256];
    __shared__ int ri[256];
    const int tid = threadIdx.x;
    const int cnt = *flagcnt;   // uniform across block

    for (int f = blockIdx.x; f < cnt; f += gridDim.x) {
        int t = flaglist[f];
        __syncthreads();
        if (tid < DIM) xsh[tid] = xg[(size_t)t * DIM + tid];
        __syncthreads();

        double best = 1.0e300;
        int bi = 0;
#pragma unroll
        for (int j = 0; j < 4; ++j) {
            int k = tid * 4 + j;   // ascending per thread
            const float* er = emb + (size_t)k * DIM;
            double m = 0.0;
            for (int d = 0; d < DIM; ++d)
                m = fma((double)xsh[d], (double)er[d], m);
            double u = se64[k] - 2.0 * m;
            if (u < best) { best = u; bi = k; }
        }
        rv[tid] = best;
        ri[tid] = bi;
        __syncthreads();
        for (int s = 128; s > 0; s >>= 1) {
            if (tid < s) {
                if (rv[tid + s] < rv[tid] ||
                    (rv[tid + s] == rv[tid] && ri[tid + s] < ri[tid])) {
                    rv[tid] = rv[tid + s];
                    ri[tid] = ri[tid + s];
                }
            }
            __syncthreads();
        }
        if (tid == 0) idx[t] = ri[0];
    }
}

// ---------------------------------------------------------------------------
// Outputs: quantized_st rows, loss partial sums, one-hot scatter + histogram
// ---------------------------------------------------------------------------
__global__ __launch_bounds__(256) void k_out(const float* __restrict__ xg,
                                             const float* __restrict__ emb,
                                             const int* __restrict__ idx,
                                             float* __restrict__ quant,
                                             float* __restrict__ enc,
                                             double* __restrict__ part,
                                             int* __restrict__ hist) {
    int g = blockIdx.x * 256 + threadIdx.x;   // 0 .. 8388607
    int n = g >> 7;
    int d = g & 127;
    int k = idx[n];
    float xv = xg[g];
    float q = emb[((size_t)k << 7) + d];
    float diff = q - xv;                      // fl(q - x), as reference
    quant[g] = xv + diff;                     // fl(x + fl(q - x))
    if (d == 0) {
        enc[((size_t)n << 10) + k] = 1.0f;
        atomicAdd(&hist[k], 1);
    }
    double sq = (double)(diff * diff);        // square in f32 like reference, sum in f64
    for (int off = 32; off > 0; off >>= 1) sq += __shfl_down(sq, off);
    __shared__ double wsum[4];
    if ((threadIdx.x & 63) == 0) wsum[threadIdx.x >> 6] = sq;
    __syncthreads();
    if (threadIdx.x == 0)
        part[blockIdx.x] = wsum[0] + wsum[1] + wsum[2] + wsum[3];
}

// ---------------------------------------------------------------------------
// Final scalars: loss mean, perplexity
// ---------------------------------------------------------------------------
__global__ __launch_bounds__(256) void k_final(const double* __restrict__ part,
                                               const int* __restrict__ hist,
                                               float* __restrict__ out_loss,
                                               float* __restrict__ out_perp) {
    __shared__ double red[256];
    const int tid = threadIdx.x;

    double s = 0.0;
    for (int i = tid; i < 32768; i += 256) s += part[i];
    red[tid] = s;
    __syncthreads();
    for (int st = 128; st > 0; st >>= 1) {
        if (tid < st) red[tid] += red[tid + st];
        __syncthreads();
    }
    double loss = red[0] / 8388608.0;
    __syncthreads();

    double e = 0.0;
    for (int b = tid; b < KCODE; b += 256) {
        double p = (double)hist[b] * (1.0 / 65536.0);
        e += p * log(p + 1e-10);
    }
    red[tid] = e;
    __syncthreads();
    for (int st = 128; st > 0; st >>= 1) {
        if (tid < st) red[tid] += red[tid + st];
        __syncthreads();
    }
    if (tid == 0) {
        *out_loss = (float)loss;
        *out_perp = (float)exp(-red[0]);
    }
}

// ---------------------------------------------------------------------------
extern "C" void kernel_launch(void* const* d_in, const int* in_sizes, int n_in,
                              void* d_out, int out_size, void* d_ws, size_t ws_size,
                              hipStream_t stream) {
    const float* x   = (const float*)d_in[0];   // 65536 x 128
    const float* emb = (const float*)d_in[1];   // 1024 x 128
    float* out = (float*)d_out;
    char* ws = (char*)d_ws;

    double* se64   = (double*)(ws + WS_SE64);
    float*  se32   = (float*)(ws + WS_SE32);
    int*    idx    = (int*)(ws + WS_IDX);
    int*    flglst = (int*)(ws + WS_FLAGLIST);
    int*    flgcnt = (int*)(ws + WS_FLAGCNT);
    int*    hist   = (int*)(ws + WS_HIST);
    double* part   = (double*)(ws + WS_PART);

    float* quant = out + OUT_QUANT_OFF;
    float* enc   = out + OUT_ENC_OFF;

    // zero the one-hot region (256 MB) and the small counters
    hipMemsetAsync(enc, 0, (size_t)N_TOK * KCODE * sizeof(float), stream);
    hipMemsetAsync(ws + WS_FLAGCNT, 0, (WS_HIST + KCODE * 4) - WS_FLAGCNT, stream);

    k_prep<<<(KCODE + 255) / 256, 256, 0, stream>>>(emb, se64, se32);
    k_main<<<N_TOK / 64, 256, 0, stream>>>(x, emb, se32, idx, flglst, flgcnt);
    k_refine<<<256, 256, 0, stream>>>(x, emb, se64, flglst, flgcnt, idx);
    k_out<<<(N_TOK * DIM) / 256, 256, 0, stream>>>(x, emb, idx, quant, enc, part, hist);
    k_final<<<1, 256, 0, stream>>>(part, hist, out, out + OUT_PERP_OFF);
}

// Round 2
// 540.840 us; speedup vs baseline: 1.3072x; 1.3072x over previous
//
#include <hip/hip_runtime.h>
#include <math.h>

#define N_TOK   65536
#define DIM     128
#define KCODE   1024

// ---- d_out element offsets ----
#define OUT_QUANT_OFF 1
#define OUT_PERP_OFF  8388609
#define OUT_ENC_OFF   8388610

// ---- workspace byte offsets ----
#define WS_SE64     0            // 1024 * 8
#define WS_SE32     8192         // 1024 * 4
#define WS_IDX      12288        // 65536 * 4
#define WS_FLAGLIST 274432       // 65536 * 4
#define WS_FLAGCNT  536576       // 4
#define WS_HIST     536704       // 1024 * 4
#define WS_PART     540800       // 32768 * 8
#define WS_EP       802944       // 1024*384*2 = 786432 -> ends 1589376

#define MARGIN 1e-5f

typedef __attribute__((ext_vector_type(8))) short short8;
typedef __attribute__((ext_vector_type(4))) float f32x4;

// RNE float -> bf16
__device__ __forceinline__ unsigned short f2bf(float f) {
    unsigned u = __float_as_uint(f);
    unsigned r = u + 0x7fffu + ((u >> 16) & 1u);
    return (unsigned short)(r >> 16);
}
__device__ __forceinline__ float bf2f(unsigned short h) {
    return __uint_as_float(((unsigned)h) << 16);
}

// ---------------------------------------------------------------------------
// se norms (f64 for refine, f32 for main epilogue)
// ---------------------------------------------------------------------------
__global__ __launch_bounds__(256) void k_prep(const float* __restrict__ emb,
                                              double* __restrict__ se64,
                                              float* __restrict__ se32) {
    int k = blockIdx.x * 256 + threadIdx.x;
    if (k >= KCODE) return;
    const float4* row = reinterpret_cast<const float4*>(emb + (size_t)k * DIM);
    double s = 0.0;
    for (int i = 0; i < DIM / 4; ++i) {
        float4 v = row[i];
        s += (double)v.x * v.x + (double)v.y * v.y + (double)v.z * v.z + (double)v.w * v.w;
    }
    se64[k] = s;
    se32[k] = (float)s;
}

// ---------------------------------------------------------------------------
// Pack x into bf16 hi/lo planes: XpHi[65536][128], XpLo[65536][128]
// (scratch inside d_out's enc region, overwritten later by k_out)
// ---------------------------------------------------------------------------
__global__ __launch_bounds__(256) void k_packx(const float* __restrict__ x,
                                               unsigned short* __restrict__ XpHi,
                                               unsigned short* __restrict__ XpLo) {
    int g = blockIdx.x * 256 + threadIdx.x;          // float4 index, 0..2097151
    float4 v = reinterpret_cast<const float4*>(x)[g];
    ushort4 h, l;
    h.x = f2bf(v.x); l.x = f2bf(v.x - bf2f(h.x));
    h.y = f2bf(v.y); l.y = f2bf(v.y - bf2f(h.y));
    h.z = f2bf(v.z); l.z = f2bf(v.z - bf2f(h.z));
    h.w = f2bf(v.w); l.w = f2bf(v.w - bf2f(h.w));
    reinterpret_cast<ushort4*>(XpHi)[g] = h;
    reinterpret_cast<ushort4*>(XpLo)[g] = l;
}

// ---------------------------------------------------------------------------
// Pack codebook: Ep[1024][384] = [-2e_hi | -2e_hi | -2e_lo]  (bf16)
// ---------------------------------------------------------------------------
__global__ __launch_bounds__(256) void k_packe(const float* __restrict__ emb,
                                               unsigned short* __restrict__ Ep) {
    int g = blockIdx.x * 256 + threadIdx.x;          // float4 index, 0..32767
    int t = g >> 5;
    int c4 = g & 31;
    float4 v = reinterpret_cast<const float4*>(emb)[g];
    ushort4 h, l;
    h.x = f2bf(v.x); l.x = f2bf(-2.0f * (v.x - bf2f(h.x)));
    h.y = f2bf(v.y); l.y = f2bf(-2.0f * (v.y - bf2f(h.y)));
    h.z = f2bf(v.z); l.z = f2bf(-2.0f * (v.z - bf2f(h.z)));
    h.w = f2bf(v.w); l.w = f2bf(-2.0f * (v.w - bf2f(h.w)));
    ushort4 h2;
    h2.x = f2bf(-2.0f * bf2f(h.x));   // exact (x2 = exponent bump)
    h2.y = f2bf(-2.0f * bf2f(h.y));
    h2.z = f2bf(-2.0f * bf2f(h.z));
    h2.w = f2bf(-2.0f * bf2f(h.w));
    unsigned short* rowp = Ep + (size_t)t * 384 + c4 * 4;
    *reinterpret_cast<ushort4*>(rowp)       = h2;
    *reinterpret_cast<ushort4*>(rowp + 128) = h2;
    *reinterpret_cast<ushort4*>(rowp + 256) = l;
}

// ---------------------------------------------------------------------------
// MFMA distance/argmin. Block = 256 thr (4 waves, 2x2), tile 128 tok x 128 code.
// K' = 384 split over 6 kchunks of 64. 8 col-chunks. 48 rounds total.
// LDS: double-buffered 2 x (As 16KB + Bs 16KB) = 64KB. global_load_lds staging.
// XOR swizzle on 16B blocks: b' = b ^ (row&7) -> 2-way max (free).
// acc = -2 x.e ; epilogue u = se + acc; track (min1,min2,idx) per token.
// ---------------------------------------------------------------------------
__global__ __launch_bounds__(256, 2) void k_main(
        const unsigned short* __restrict__ XpHi,
        const unsigned short* __restrict__ XpLo,
        const unsigned short* __restrict__ Ep,
        const float* __restrict__ se32,
        int* __restrict__ idx,
        int* __restrict__ flaglist,
        int* __restrict__ flagcnt) {
    __shared__ char lds[2][32768];

    const int tid  = threadIdx.x;
    const int lane = tid & 63;
    const int w    = tid >> 6;
    const int l15  = lane & 15;
    const int quad = lane >> 4;
    const int wr   = w >> 1;
    const int wc   = w & 1;
    const int tok0 = blockIdx.x * 128;

    auto stage = [&](int cc, int kc, int buf) {
        const unsigned short* xsrc = (kc == 2 || kc == 3) ? XpLo : XpHi;
        const int koff = (kc & 1) * 64;              // ushort units (64 bf16 = 128B)
#pragma unroll
        for (int i = 0; i < 4; ++i) {
            int L = (w * 4 + i) * 64 + lane;
            int row = L >> 3;
            int b = (L & 7) ^ (row & 7);
            const unsigned short* src = xsrc + (size_t)(tok0 + row) * 128 + koff + b * 8;
            char* dst = &lds[buf][(w * 4 + i) * 1024];
            __builtin_amdgcn_global_load_lds(
                (const __attribute__((address_space(1))) unsigned int*)src,
                (__attribute__((address_space(3))) unsigned int*)dst, 16, 0, 0);
        }
#pragma unroll
        for (int i = 0; i < 4; ++i) {
            int j = w * 4 + i;
            int L = j * 64 + lane;
            int c = L >> 3;
            int b = (L & 7) ^ (c & 7);
            const unsigned short* src = Ep + (size_t)(cc * 128 + c) * 384 + kc * 64 + b * 8;
            char* dst = &lds[buf][16384 + j * 1024];
            __builtin_amdgcn_global_load_lds(
                (const __attribute__((address_space(1))) unsigned int*)src,
                (__attribute__((address_space(3))) unsigned int*)dst, 16, 0, 0);
        }
    };

    f32x4 acc[4][4];
#pragma unroll
    for (int a = 0; a < 4; ++a)
#pragma unroll
        for (int b = 0; b < 4; ++b) acc[a][b] = (f32x4){0.f, 0.f, 0.f, 0.f};

    float v1[16], v2[16];
    int   i1[16];
#pragma unroll
    for (int s = 0; s < 16; ++s) { v1[s] = 3.0e38f; v2[s] = 3.0e38f; i1[s] = 0; }

    int cc = 0, kc = 0;
    stage(0, 0, 0);

    for (int r = 0; r < 48; ++r) {
        __syncthreads();                 // drains stage(r); protects buf being rewritten
        int ncc = cc, nkc = kc + 1;
        if (nkc == 6) { nkc = 0; ncc = cc + 1; }
        if (r + 1 < 48) stage(ncc, nkc, (r + 1) & 1);   // async prefetch under compute

        const char* Ab = lds[r & 1];
        const char* Bb = lds[r & 1] + 16384;
#pragma unroll
        for (int ks = 0; ks < 2; ++ks) {
            const int bq = ks * 4 + quad;
            short8 av[4], bv[4];
#pragma unroll
            for (int ti = 0; ti < 4; ++ti) {
                int m = wr * 64 + ti * 16 + l15;
                av[ti] = *reinterpret_cast<const short8*>(Ab + (m * 8 + (bq ^ (m & 7))) * 16);
            }
#pragma unroll
            for (int tj = 0; tj < 4; ++tj) {
                int c = wc * 64 + tj * 16 + l15;
                bv[tj] = *reinterpret_cast<const short8*>(Bb + (c * 8 + (bq ^ (c & 7))) * 16);
            }
#pragma unroll
            for (int ti = 0; ti < 4; ++ti)
#pragma unroll
                for (int tj = 0; tj < 4; ++tj)
                    acc[ti][tj] = __builtin_amdgcn_mfma_f32_16x16x32_bf16(
                        av[ti], bv[tj], acc[ti][tj], 0, 0, 0);
        }

        if (kc == 5) {   // finished this 128-code col-chunk: argmin update
#pragma unroll
            for (int tj = 0; tj < 4; ++tj) {
                int cg = cc * 128 + wc * 64 + tj * 16 + l15;
                float se = se32[cg];
#pragma unroll
                for (int ti = 0; ti < 4; ++ti) {
                    f32x4 A = acc[ti][tj];
#pragma unroll
                    for (int rr = 0; rr < 4; ++rr) {
                        float u = se + A[rr];
                        int s = ti * 4 + rr;
                        if (u < v1[s]) { v2[s] = v1[s]; v1[s] = u; i1[s] = cg; }
                        else if (u < v2[s]) v2[s] = u;
                    }
                    acc[ti][tj] = (f32x4){0.f, 0.f, 0.f, 0.f};
                }
            }
        }
        cc = ncc; kc = nkc;
    }

    // cross-lane / cross-wave argmin reduction through LDS
    __syncthreads();
    float* v1L = reinterpret_cast<float*>(&lds[0][0]);       // 4096 f
    float* v2L = reinterpret_cast<float*>(&lds[0][16384]);   // 4096 f
    int*   i1L = reinterpret_cast<int*>(&lds[1][0]);         // 4096 i
#pragma unroll
    for (int ti = 0; ti < 4; ++ti)
#pragma unroll
        for (int rr = 0; rr < 4; ++rr) {
            int t_local = wr * 64 + ti * 16 + quad * 4 + rr;
            int slot = (t_local * 2 + wc) * 16 + l15;
            v1L[slot] = v1[ti * 4 + rr];
            v2L[slot] = v2[ti * 4 + rr];
            i1L[slot] = i1[ti * 4 + rr];
        }
    __syncthreads();

    if (tid < 128) {
        int base = tid * 32;
        float V1 = v1L[base], V2 = v2L[base];
        int I = i1L[base];
        for (int j = 1; j < 32; ++j) {
            float b1 = v1L[base + j];
            float b2 = v2L[base + j];
            int bi = i1L[base + j];
            if (b1 < V1 || (b1 == V1 && bi < I)) { V2 = fminf(V1, b2); V1 = b1; I = bi; }
            else V2 = fminf(V2, b1);
        }
        idx[tok0 + tid] = I;
        if (V2 - V1 < MARGIN) {
            int p = atomicAdd(flagcnt, 1);
            flaglist[p] = tok0 + tid;
        }
    }
}

// ---------------------------------------------------------------------------
// fp64 full rescan for near-tie tokens
// ---------------------------------------------------------------------------
__global__ __launch_bounds__(256) void k_refine(const float* __restrict__ xg,
                                                const float* __restrict__ emb,
                                                const double* __restrict__ se64,
                                                const int* __restrict__ flaglist,
                                                const int* __restrict__ flagcnt,
                                                int* __restrict__ idx) {
    __shared__ float xsh[DIM];
    __shared__ double rv[256];
    __shared__ int ri[256];
    const int tid = threadIdx.x;
    const int cnt = *flagcnt;

    for (int f = blockIdx.x; f < cnt; f += gridDim.x) {
        int t = flaglist[f];
        __syncthreads();
        if (tid < DIM) xsh[tid] = xg[(size_t)t * DIM + tid];
        __syncthreads();

        double best = 1.0e300;
        int bi = 0;
#pragma unroll
        for (int j = 0; j < 4; ++j) {
            int k = tid * 4 + j;
            const float* er = emb + (size_t)k * DIM;
            double m = 0.0;
            for (int d = 0; d < DIM; ++d)
                m = fma((double)xsh[d], (double)er[d], m);
            double u = se64[k] - 2.0 * m;
            if (u < best) { best = u; bi = k; }
        }
        rv[tid] = best;
        ri[tid] = bi;
        __syncthreads();
        for (int s = 128; s > 0; s >>= 1) {
            if (tid < s) {
                if (rv[tid + s] < rv[tid] ||
                    (rv[tid + s] == rv[tid] && ri[tid + s] < ri[tid])) {
                    rv[tid] = rv[tid + s];
                    ri[tid] = ri[tid + s];
                }
            }
            __syncthreads();
        }
        if (tid == 0) idx[t] = ri[0];
    }
}

// ---------------------------------------------------------------------------
// Outputs: 2 tokens per block. Writes quantized_st rows, the FULL one-hot rows
// (zeros + one), loss partials, histogram. No separate memset needed.
// ---------------------------------------------------------------------------
__global__ __launch_bounds__(256) void k_out(const float* __restrict__ xg,
                                             const float* __restrict__ emb,
                                             const int* __restrict__ idx,
                                             float* __restrict__ quant,
                                             float* __restrict__ enc,
                                             double* __restrict__ part,
                                             int* __restrict__ hist) {
    const int tid = threadIdx.x;
    const int token = blockIdx.x * 2 + (tid >> 7);
    const int d = tid & 127;
    const int k = idx[token];

    size_t g = ((size_t)token << 7) + d;
    float xv = xg[g];
    float q  = emb[((size_t)k << 7) + d];
    float diff = q - xv;
    quant[g] = xv + diff;

    // one-hot: 8 floats per thread, 8B stores (enc base is 8B- but not 16B-aligned)
    int c0 = d * 8;
    int rk = k - c0;
    float2* ebase = reinterpret_cast<float2*>(enc + ((size_t)token << 10) + c0);
#pragma unroll
    for (int h = 0; h < 4; ++h) {
        float2 z;
        z.x = (rk == 2 * h)     ? 1.0f : 0.0f;
        z.y = (rk == 2 * h + 1) ? 1.0f : 0.0f;
        ebase[h] = z;
    }
    if (d == 0) atomicAdd(&hist[k], 1);

    double sq = (double)(diff * diff);
    for (int off = 32; off > 0; off >>= 1) sq += __shfl_down(sq, off);
    __shared__ double wsum[4];
    if ((tid & 63) == 0) wsum[tid >> 6] = sq;
    __syncthreads();
    if (tid == 0) part[blockIdx.x] = wsum[0] + wsum[1] + wsum[2] + wsum[3];
}

// ---------------------------------------------------------------------------
__global__ __launch_bounds__(256) void k_final(const double* __restrict__ part,
                                               const int* __restrict__ hist,
                                               float* __restrict__ out_loss,
                                               float* __restrict__ out_perp) {
    __shared__ double red[256];
    const int tid = threadIdx.x;

    double s = 0.0;
    for (int i = tid; i < 32768; i += 256) s += part[i];
    red[tid] = s;
    __syncthreads();
    for (int st = 128; st > 0; st >>= 1) {
        if (tid < st) red[tid] += red[tid + st];
        __syncthreads();
    }
    double loss = red[0] / 8388608.0;
    __syncthreads();

    double e = 0.0;
    for (int b = tid; b < KCODE; b += 256) {
        double p = (double)hist[b] * (1.0 / 65536.0);
        e += p * log(p + 1e-10);
    }
    red[tid] = e;
    __syncthreads();
    for (int st = 128; st > 0; st >>= 1) {
        if (tid < st) red[tid] += red[tid + st];
        __syncthreads();
    }
    if (tid == 0) {
        *out_loss = (float)loss;
        *out_perp = (float)exp(-red[0]);
    }
}

// ---------------------------------------------------------------------------
extern "C" void kernel_launch(void* const* d_in, const int* in_sizes, int n_in,
                              void* d_out, int out_size, void* d_ws, size_t ws_size,
                              hipStream_t stream) {
    const float* x   = (const float*)d_in[0];
    const float* emb = (const float*)d_in[1];
    float* out = (float*)d_out;
    char*  ws  = (char*)d_ws;

    double* se64   = (double*)(ws + WS_SE64);
    float*  se32   = (float*)(ws + WS_SE32);
    int*    idx    = (int*)(ws + WS_IDX);
    int*    flglst = (int*)(ws + WS_FLAGLIST);
    int*    flgcnt = (int*)(ws + WS_FLAGCNT);
    int*    hist   = (int*)(ws + WS_HIST);
    double* part   = (double*)(ws + WS_PART);
    unsigned short* Ep = (unsigned short*)(ws + WS_EP);

    float* quant = out + OUT_QUANT_OFF;
    float* enc   = out + OUT_ENC_OFF;

    // bf16 x-planes scratch inside the enc output region (dead until k_out)
    unsigned short* XpHi = (unsigned short*)(((uintptr_t)enc + 255) & ~(uintptr_t)255);
    unsigned short* XpLo = XpHi + (size_t)N_TOK * DIM;

    hipMemsetAsync(ws + WS_FLAGCNT, 0, (WS_HIST + KCODE * 4) - WS_FLAGCNT, stream);

    k_prep <<<(KCODE + 255) / 256, 256, 0, stream>>>(emb, se64, se32);
    k_packe<<<KCODE * (DIM / 4) / 256, 256, 0, stream>>>(emb, Ep);
    k_packx<<<N_TOK * (DIM / 4) / 256, 256, 0, stream>>>(x, XpHi, XpLo);
    k_main <<<N_TOK / 128, 256, 0, stream>>>(XpHi, XpLo, Ep, se32, idx, flglst, flgcnt);
    k_refine<<<256, 256, 0, stream>>>(x, emb, se64, flglst, flgcnt, idx);
    k_out  <<<N_TOK / 2, 256, 0, stream>>>(x, emb, idx, quant, enc, part, hist);
    k_final<<<1, 256, 0, stream>>>(part, hist, out, out + OUT_PERP_OFF);
}

// Round 3
// 472.508 us; speedup vs baseline: 1.4962x; 1.1446x over previous
//
#include <hip/hip_runtime.h>
#include <math.h>

#define N_TOK   65536
#define DIM     128
#define KCODE   1024

// ---- d_out element offsets ----
#define OUT_QUANT_OFF 1
#define OUT_PERP_OFF  8388609
#define OUT_ENC_OFF   8388610

// ---- workspace byte offsets ----
#define WS_SE64     0            // 1024 * 8
#define WS_SE32     8192         // 1024 * 4
#define WS_IDX      12288        // 65536 * 4        -> 274432
#define WS_FLAGLIST 274432       // 65536 * 4        -> 536576
#define WS_FLAGCNT  536576       // 4 (pad to 128)
#define WS_HIST     536704       // 1024 * 4         -> 540800
#define WS_PART     540800       // 32768 * 8        -> 802944
#define WS_EP       802944       // 1024*128*2 f16   -> 1065088

#define MARGIN 5e-5f
#define INV2048X2 9.765625e-4f   // 2/2048, exact

typedef _Float16 half8 __attribute__((ext_vector_type(8)));
typedef _Float16 half4 __attribute__((ext_vector_type(4)));
typedef __attribute__((ext_vector_type(4))) float f32x4;

// ---------------------------------------------------------------------------
// Codebook prep: se norms (f64 + f32) and f16 pack Ep[k][d] = f16(-2048 * e)
// 128 blocks x 256 thr; 8 rows/block, 32 threads/row.
// ---------------------------------------------------------------------------
__global__ __launch_bounds__(256) void k_code(const float* __restrict__ emb,
                                              double* __restrict__ se64,
                                              float* __restrict__ se32,
                                              unsigned short* __restrict__ Ep) {
    const int tid = threadIdx.x;
    const int sub = tid & 31;
    const int row = blockIdx.x * 8 + (tid >> 5);
    float4 v = reinterpret_cast<const float4*>(emb + ((size_t)row << 7))[sub];

    double s = (double)v.x * v.x + (double)v.y * v.y
             + (double)v.z * v.z + (double)v.w * v.w;
#pragma unroll
    for (int m = 16; m > 0; m >>= 1) s += __shfl_xor(s, m);
    if (sub == 0) { se64[row] = s; se32[row] = (float)s; }

    half4 hv;
    hv[0] = (_Float16)(-2048.0f * v.x);
    hv[1] = (_Float16)(-2048.0f * v.y);
    hv[2] = (_Float16)(-2048.0f * v.z);
    hv[3] = (_Float16)(-2048.0f * v.w);
    *reinterpret_cast<half4*>(Ep + ((size_t)row << 7) + sub * 4) = hv;
}

// ---------------------------------------------------------------------------
// MFMA f16 distance/argmin. Block = 256 thr (4 waves 2x2), tile 128 tok x 1024
// codes, K=128. A (32KB f16) staged once w/ in-kernel f32->f16; A-frags live
// in regs. B: 16 chunks of 64 codes (16KB), double-buffered global_load_lds.
// LDS 64KB -> 2 blocks/CU. Swizzle: 16B-block b' = b ^ (row & 7).
// acc = -2048 * x.e ; u = se + acc * 2^-11*2 ; track (min1,min2,idx).
// ---------------------------------------------------------------------------
__global__ __launch_bounds__(256, 2) void k_main(
        const float* __restrict__ xg,
        const unsigned short* __restrict__ Ep,
        const float* __restrict__ se32,
        int* __restrict__ idx,
        int* __restrict__ flaglist,
        int* __restrict__ flagcnt) {
    __shared__ char lds[65536];    // A: [0,32768) ; B: 32768 + buf*16384

    const int tid  = threadIdx.x;
    const int lane = tid & 63;
    const int w    = tid >> 6;
    const int l15  = lane & 15;
    const int quad = lane >> 4;
    const int wr   = w >> 1;
    const int wc   = w & 1;
    const int tok0 = blockIdx.x * 128;

    auto stageB = [&](int ch, int buf) {
#pragma unroll
        for (int it = 0; it < 4; ++it) {
            int L = it * 256 + w * 64 + lane;
            int c = L >> 4;
            int p = L & 15;
            const unsigned short* src =
                Ep + ((size_t)(ch * 64 + c) << 7) + ((p ^ (c & 7)) << 3);
            char* dst = lds + 32768 + buf * 16384 + (it * 256 + w * 64) * 16;
            __builtin_amdgcn_global_load_lds(
                (const __attribute__((address_space(1))) unsigned int*)src,
                (__attribute__((address_space(3))) unsigned int*)dst, 16, 0, 0);
        }
    };

    stageB(0, 0);

    // ---- stage A: 2 threads/row, f32 load -> f16 convert -> swizzled ds_write
    {
        const int r = tid >> 1;
        const int h = tid & 1;
        const float4* src =
            reinterpret_cast<const float4*>(xg + (((size_t)(tok0 + r)) << 7) + (h << 6));
#pragma unroll
        for (int p = 0; p < 8; ++p) {
            float4 f0 = src[2 * p];
            float4 f1 = src[2 * p + 1];
            half8 hv;
            hv[0] = (_Float16)f0.x; hv[1] = (_Float16)f0.y;
            hv[2] = (_Float16)f0.z; hv[3] = (_Float16)f0.w;
            hv[4] = (_Float16)f1.x; hv[5] = (_Float16)f1.y;
            hv[6] = (_Float16)f1.z; hv[7] = (_Float16)f1.w;
            int b = (h << 3) + p;
            int slot = (r << 4) + (b ^ (r & 7));
            *reinterpret_cast<half8*>(lds + slot * 16) = hv;
        }
    }
    __syncthreads();   // drains A ds_writes + B chunk-0 loads

    // ---- preload all A fragments into registers (64 VGPRs)
    half8 av[4][4];
#pragma unroll
    for (int ti = 0; ti < 4; ++ti)
#pragma unroll
        for (int ks = 0; ks < 4; ++ks) {
            int m = wr * 64 + ti * 16 + l15;
            av[ti][ks] = *reinterpret_cast<const half8*>(
                lds + ((m << 4) + ((ks * 4 + quad) ^ (m & 7))) * 16);
        }

    float v1[16], v2[16];
    int   i1[16];
#pragma unroll
    for (int s = 0; s < 16; ++s) { v1[s] = 3.0e38f; v2[s] = 3.0e38f; i1[s] = 0; }

    for (int ch = 0; ch < 16; ++ch) {
        if (ch + 1 < 16) stageB(ch + 1, (ch + 1) & 1);   // prefetch under compute

        const char* Bb = lds + 32768 + (ch & 1) * 16384;
        f32x4 acc[4][2];
#pragma unroll
        for (int ti = 0; ti < 4; ++ti) {
            acc[ti][0] = (f32x4){0.f, 0.f, 0.f, 0.f};
            acc[ti][1] = (f32x4){0.f, 0.f, 0.f, 0.f};
        }

#pragma unroll
        for (int ks = 0; ks < 4; ++ks) {
            int c0 = wc * 32 + l15;
            int c1 = c0 + 16;
            half8 bv0 = *reinterpret_cast<const half8*>(
                Bb + ((c0 << 4) + ((ks * 4 + quad) ^ (c0 & 7))) * 16);
            half8 bv1 = *reinterpret_cast<const half8*>(
                Bb + ((c1 << 4) + ((ks * 4 + quad) ^ (c1 & 7))) * 16);
#pragma unroll
            for (int ti = 0; ti < 4; ++ti) {
                acc[ti][0] = __builtin_amdgcn_mfma_f32_16x16x32_f16(
                    av[ti][ks], bv0, acc[ti][0], 0, 0, 0);
                acc[ti][1] = __builtin_amdgcn_mfma_f32_16x16x32_f16(
                    av[ti][ks], bv1, acc[ti][1], 0, 0, 0);
            }
        }

        // epilogue: u = se + acc * 2/2048 ; 5 VALU ops per value
#pragma unroll
        for (int tj = 0; tj < 2; ++tj) {
            int cg = ch * 64 + wc * 32 + tj * 16 + l15;
            float se = se32[cg];
#pragma unroll
            for (int ti = 0; ti < 4; ++ti) {
                f32x4 A = acc[ti][tj];
#pragma unroll
                for (int rr = 0; rr < 4; ++rr) {
                    float u = fmaf(A[rr], INV2048X2, se);
                    int s = ti * 4 + rr;
                    float p1 = v1[s];
                    v2[s] = fminf(fmaxf(u, p1), v2[s]);   // med3(v2, v1, u)
                    bool c = u < p1;
                    v1[s] = c ? u : p1;
                    i1[s] = c ? cg : i1[s];
                }
            }
        }
        __syncthreads();   // drain prefetch; protect buf reuse
    }

    // ---- cross-lane/wave argmin reduction (reuse LDS)
    float* v1L = reinterpret_cast<float*>(lds);            // 4096 f
    float* v2L = reinterpret_cast<float*>(lds + 16384);    // 4096 f
    int*   i1L = reinterpret_cast<int*>(lds + 32768);      // 4096 i
#pragma unroll
    for (int ti = 0; ti < 4; ++ti)
#pragma unroll
        for (int rr = 0; rr < 4; ++rr) {
            int t_local = wr * 64 + ti * 16 + quad * 4 + rr;
            int slot = t_local * 32 + wc * 16 + l15;
            v1L[slot] = v1[ti * 4 + rr];
            v2L[slot] = v2[ti * 4 + rr];
            i1L[slot] = i1[ti * 4 + rr];
        }
    __syncthreads();

    if (tid < 128) {
        int base = tid * 32;
        float V1 = v1L[base], V2 = v2L[base];
        int I = i1L[base];
        for (int j = 1; j < 32; ++j) {
            float b1 = v1L[base + j];
            float b2 = v2L[base + j];
            int bi = i1L[base + j];
            if (b1 < V1 || (b1 == V1 && bi < I)) { V2 = fminf(V1, b2); V1 = b1; I = bi; }
            else V2 = fminf(V2, b1);
        }
        idx[tok0 + tid] = I;
        if (V2 - V1 < MARGIN) {
            int p = atomicAdd(flagcnt, 1);
            flaglist[p] = tok0 + tid;
        }
    }
}

// ---------------------------------------------------------------------------
// fp64 full rescan for near-tie tokens (~1-2% expected)
// ---------------------------------------------------------------------------
__global__ __launch_bounds__(256) void k_refine(const float* __restrict__ xg,
                                                const float* __restrict__ emb,
                                                const double* __restrict__ se64,
                                                const int* __restrict__ flaglist,
                                                const int* __restrict__ flagcnt,
                                                int* __restrict__ idx) {
    __shared__ float xsh[DIM];
    __shared__ double rv[256];
    __shared__ int ri[256];
    const int tid = threadIdx.x;
    const int cnt = *flagcnt;

    for (int f = blockIdx.x; f < cnt; f += gridDim.x) {
        int t = flaglist[f];
        __syncthreads();
        if (tid < DIM) xsh[tid] = xg[(size_t)t * DIM + tid];
        __syncthreads();

        double best = 1.0e300;
        int bi = 0;
#pragma unroll
        for (int j = 0; j < 4; ++j) {
            int k = tid * 4 + j;
            const float* er = emb + (size_t)k * DIM;
            double m = 0.0;
            for (int d = 0; d < DIM; ++d)
                m = fma((double)xsh[d], (double)er[d], m);
            double u = se64[k] - 2.0 * m;
            if (u < best) { best = u; bi = k; }
        }
        rv[tid] = best;
        ri[tid] = bi;
        __syncthreads();
        for (int s = 128; s > 0; s >>= 1) {
            if (tid < s) {
                if (rv[tid + s] < rv[tid] ||
                    (rv[tid + s] == rv[tid] && ri[tid + s] < ri[tid])) {
                    rv[tid] = rv[tid + s];
                    ri[tid] = ri[tid + s];
                }
            }
            __syncthreads();
        }
        if (tid == 0) idx[t] = ri[0];
    }
}

// ---------------------------------------------------------------------------
// Outputs: 2 tokens/block. quantized_st rows + FULL one-hot rows (zeros+one),
// loss partials, histogram. No big memset needed.
// ---------------------------------------------------------------------------
__global__ __launch_bounds__(256) void k_out(const float* __restrict__ xg,
                                             const float* __restrict__ emb,
                                             const int* __restrict__ idx,
                                             float* __restrict__ quant,
                                             float* __restrict__ enc,
                                             double* __restrict__ part,
                                             int* __restrict__ hist) {
    const int tid = threadIdx.x;
    const int token = blockIdx.x * 2 + (tid >> 7);
    const int d = tid & 127;
    const int k = idx[token];

    size_t g = ((size_t)token << 7) + d;
    float xv = xg[g];
    float q  = emb[((size_t)k << 7) + d];
    float diff = q - xv;
    quant[g] = xv + diff;

    int c0 = d * 8;
    int rk = k - c0;
    float2* ebase = reinterpret_cast<float2*>(enc + ((size_t)token << 10) + c0);
#pragma unroll
    for (int h = 0; h < 4; ++h) {
        float2 z;
        z.x = (rk == 2 * h)     ? 1.0f : 0.0f;
        z.y = (rk == 2 * h + 1) ? 1.0f : 0.0f;
        ebase[h] = z;
    }
    if (d == 0) atomicAdd(&hist[k], 1);

    double sq = (double)(diff * diff);
    for (int off = 32; off > 0; off >>= 1) sq += __shfl_down(sq, off);
    __shared__ double wsum[4];
    if ((tid & 63) == 0) wsum[tid >> 6] = sq;
    __syncthreads();
    if (tid == 0) part[blockIdx.x] = wsum[0] + wsum[1] + wsum[2] + wsum[3];
}

// ---------------------------------------------------------------------------
__global__ __launch_bounds__(256) void k_final(const double* __restrict__ part,
                                               const int* __restrict__ hist,
                                               float* __restrict__ out_loss,
                                               float* __restrict__ out_perp) {
    __shared__ double red[256];
    const int tid = threadIdx.x;

    double s = 0.0;
    for (int i = tid; i < 32768; i += 256) s += part[i];
    red[tid] = s;
    __syncthreads();
    for (int st = 128; st > 0; st >>= 1) {
        if (tid < st) red[tid] += red[tid + st];
        __syncthreads();
    }
    double loss = red[0] / 8388608.0;
    __syncthreads();

    double e = 0.0;
    for (int b = tid; b < KCODE; b += 256) {
        double p = (double)hist[b] * (1.0 / 65536.0);
        e += p * log(p + 1e-10);
    }
    red[tid] = e;
    __syncthreads();
    for (int st = 128; st > 0; st >>= 1) {
        if (tid < st) red[tid] += red[tid + st];
        __syncthreads();
    }
    if (tid == 0) {
        *out_loss = (float)loss;
        *out_perp = (float)exp(-red[0]);
    }
}

// ---------------------------------------------------------------------------
extern "C" void kernel_launch(void* const* d_in, const int* in_sizes, int n_in,
                              void* d_out, int out_size, void* d_ws, size_t ws_size,
                              hipStream_t stream) {
    const float* x   = (const float*)d_in[0];
    const float* emb = (const float*)d_in[1];
    float* out = (float*)d_out;
    char*  ws  = (char*)d_ws;

    double* se64   = (double*)(ws + WS_SE64);
    float*  se32   = (float*)(ws + WS_SE32);
    int*    idx    = (int*)(ws + WS_IDX);
    int*    flglst = (int*)(ws + WS_FLAGLIST);
    int*    flgcnt = (int*)(ws + WS_FLAGCNT);
    int*    hist   = (int*)(ws + WS_HIST);
    double* part   = (double*)(ws + WS_PART);
    unsigned short* Ep = (unsigned short*)(ws + WS_EP);

    float* quant = out + OUT_QUANT_OFF;
    float* enc   = out + OUT_ENC_OFF;

    hipMemsetAsync(ws + WS_FLAGCNT, 0, (WS_HIST + KCODE * 4) - WS_FLAGCNT, stream);

    k_code <<<KCODE / 8, 256, 0, stream>>>(emb, se64, se32, Ep);
    k_main <<<N_TOK / 128, 256, 0, stream>>>(x, Ep, se32, idx, flglst, flgcnt);
    k_refine<<<256, 256, 0, stream>>>(x, emb, se64, flglst, flgcnt, idx);
    k_out  <<<N_TOK / 2, 256, 0, stream>>>(x, emb, idx, quant, enc, part, hist);
    k_final<<<1, 256, 0, stream>>>(part, hist, out, out + OUT_PERP_OFF);
}

// Round 4
// 436.357 us; speedup vs baseline: 1.6202x; 1.0828x over previous
//
#include <hip/hip_runtime.h>
#include <math.h>

#define N_TOK   65536
#define DIM     128
#define KCODE   1024

// ---- d_out element offsets ----
#define OUT_QUANT_OFF 1
#define OUT_PERP_OFF  8388609
#define OUT_ENC_OFF   8388610

// ---- workspace byte offsets ----
#define WS_SE64     0            // 1024 * 8
#define WS_SE32     8192         // 1024 * 4
#define WS_IDX      12288        // 65536 * 4        -> 274432
#define WS_FLAGLIST 274432       // 65536 * 4        -> 536576
#define WS_FLAGCNT  536576       // 4
#define WS_LOSSX    536584       // 8 (f64 loss patch accumulator)
#define WS_HIST     536704       // 1024 * 4         -> 540800
#define WS_PART     540800       // 512 * 8          -> 544896
#define WS_EP       802944       // 1024*128*2 f16   -> 1065088

#define MARGIN 5e-5f
#define INV2048X2 9.765625e-4f   // 2/2048, exact

typedef _Float16 half8 __attribute__((ext_vector_type(8)));
typedef _Float16 half4 __attribute__((ext_vector_type(4)));
typedef __attribute__((ext_vector_type(4))) float f32x4;

// ---------------------------------------------------------------------------
// Codebook prep: se norms (f64 + f32) and f16 pack Ep[k][d] = f16(-2048 * e)
// ---------------------------------------------------------------------------
__global__ __launch_bounds__(256) void k_code(const float* __restrict__ emb,
                                              double* __restrict__ se64,
                                              float* __restrict__ se32,
                                              unsigned short* __restrict__ Ep) {
    const int tid = threadIdx.x;
    const int sub = tid & 31;
    const int row = blockIdx.x * 8 + (tid >> 5);
    float4 v = reinterpret_cast<const float4*>(emb + ((size_t)row << 7))[sub];

    double s = (double)v.x * v.x + (double)v.y * v.y
             + (double)v.z * v.z + (double)v.w * v.w;
#pragma unroll
    for (int m = 16; m > 0; m >>= 1) s += __shfl_xor(s, m);
    if (sub == 0) { se64[row] = s; se32[row] = (float)s; }

    half4 hv;
    hv[0] = (_Float16)(-2048.0f * v.x);
    hv[1] = (_Float16)(-2048.0f * v.y);
    hv[2] = (_Float16)(-2048.0f * v.z);
    hv[3] = (_Float16)(-2048.0f * v.w);
    *reinterpret_cast<half4*>(Ep + ((size_t)row << 7) + sub * 4) = hv;
}

// ---------------------------------------------------------------------------
// FUSED: f16 MFMA distance/argmin + full output writes.
// Block = 256 thr (4 waves 2x2), 128 tokens x 1024 codes, K=128.
// Phase 1: A staged once (f32->f16 in-kernel), frags in regs; B double-
//          buffered 16KB chunks via global_load_lds. Track (min1,min2,idx).
// Phase 2: same block streams enc rows (512KB, coalesced), quant rows
//          (x re-read, L2-warm), f64 loss partial, hist atomics.
// ---------------------------------------------------------------------------
__global__ __launch_bounds__(256, 2) void k_main(
        const float* __restrict__ xg,
        const float* __restrict__ emb,
        const unsigned short* __restrict__ Ep,
        const float* __restrict__ se32,
        int* __restrict__ idx,
        int* __restrict__ flaglist,
        int* __restrict__ flagcnt,
        float* __restrict__ quant,
        float* __restrict__ enc,
        double* __restrict__ part,
        int* __restrict__ hist) {
    __shared__ char lds[65536];    // A: [0,32768) ; B: 32768 + buf*16384

    const int tid  = threadIdx.x;
    const int lane = tid & 63;
    const int w    = tid >> 6;
    const int l15  = lane & 15;
    const int quad = lane >> 4;
    const int wr   = w >> 1;
    const int wc   = w & 1;
    const int tok0 = blockIdx.x * 128;

    auto stageB = [&](int ch, int buf) {
#pragma unroll
        for (int it = 0; it < 4; ++it) {
            int L = it * 256 + w * 64 + lane;
            int c = L >> 4;
            int p = L & 15;
            const unsigned short* src =
                Ep + ((size_t)(ch * 64 + c) << 7) + ((p ^ (c & 7)) << 3);
            char* dst = lds + 32768 + buf * 16384 + (it * 256 + w * 64) * 16;
            __builtin_amdgcn_global_load_lds(
                (const __attribute__((address_space(1))) unsigned int*)src,
                (__attribute__((address_space(3))) unsigned int*)dst, 16, 0, 0);
        }
    };

    stageB(0, 0);

    // ---- stage A: 2 threads/row, f32 load -> f16 convert -> swizzled ds_write
    {
        const int r = tid >> 1;
        const int h = tid & 1;
        const float4* src =
            reinterpret_cast<const float4*>(xg + (((size_t)(tok0 + r)) << 7) + (h << 6));
#pragma unroll
        for (int p = 0; p < 8; ++p) {
            float4 f0 = src[2 * p];
            float4 f1 = src[2 * p + 1];
            half8 hv;
            hv[0] = (_Float16)f0.x; hv[1] = (_Float16)f0.y;
            hv[2] = (_Float16)f0.z; hv[3] = (_Float16)f0.w;
            hv[4] = (_Float16)f1.x; hv[5] = (_Float16)f1.y;
            hv[6] = (_Float16)f1.z; hv[7] = (_Float16)f1.w;
            int b = (h << 3) + p;
            int slot = (r << 4) + (b ^ (r & 7));
            *reinterpret_cast<half8*>(lds + slot * 16) = hv;
        }
    }
    __syncthreads();

    // ---- preload all A fragments into registers
    half8 av[4][4];
#pragma unroll
    for (int ti = 0; ti < 4; ++ti)
#pragma unroll
        for (int ks = 0; ks < 4; ++ks) {
            int m = wr * 64 + ti * 16 + l15;
            av[ti][ks] = *reinterpret_cast<const half8*>(
                lds + ((m << 4) + ((ks * 4 + quad) ^ (m & 7))) * 16);
        }

    float v1[16], v2[16];
    int   i1[16];
#pragma unroll
    for (int s = 0; s < 16; ++s) { v1[s] = 3.0e38f; v2[s] = 3.0e38f; i1[s] = 0; }

    for (int ch = 0; ch < 16; ++ch) {
        if (ch + 1 < 16) stageB(ch + 1, (ch + 1) & 1);

        const char* Bb = lds + 32768 + (ch & 1) * 16384;
        f32x4 acc[4][2];
#pragma unroll
        for (int ti = 0; ti < 4; ++ti) {
            acc[ti][0] = (f32x4){0.f, 0.f, 0.f, 0.f};
            acc[ti][1] = (f32x4){0.f, 0.f, 0.f, 0.f};
        }

#pragma unroll
        for (int ks = 0; ks < 4; ++ks) {
            int c0 = wc * 32 + l15;
            int c1 = c0 + 16;
            half8 bv0 = *reinterpret_cast<const half8*>(
                Bb + ((c0 << 4) + ((ks * 4 + quad) ^ (c0 & 7))) * 16);
            half8 bv1 = *reinterpret_cast<const half8*>(
                Bb + ((c1 << 4) + ((ks * 4 + quad) ^ (c1 & 7))) * 16);
#pragma unroll
            for (int ti = 0; ti < 4; ++ti) {
                acc[ti][0] = __builtin_amdgcn_mfma_f32_16x16x32_f16(
                    av[ti][ks], bv0, acc[ti][0], 0, 0, 0);
                acc[ti][1] = __builtin_amdgcn_mfma_f32_16x16x32_f16(
                    av[ti][ks], bv1, acc[ti][1], 0, 0, 0);
            }
        }

#pragma unroll
        for (int tj = 0; tj < 2; ++tj) {
            int cg = ch * 64 + wc * 32 + tj * 16 + l15;
            float se = se32[cg];
#pragma unroll
            for (int ti = 0; ti < 4; ++ti) {
                f32x4 A = acc[ti][tj];
#pragma unroll
                for (int rr = 0; rr < 4; ++rr) {
                    float u = fmaf(A[rr], INV2048X2, se);
                    int s = ti * 4 + rr;
                    float p1 = v1[s];
                    v2[s] = fminf(fmaxf(u, p1), v2[s]);   // med3
                    bool c = u < p1;
                    v1[s] = c ? u : p1;
                    i1[s] = c ? cg : i1[s];
                }
            }
        }
        __syncthreads();
    }

    // ---- cross-lane/wave argmin reduction
    float* v1L = reinterpret_cast<float*>(lds);            // 16KB
    float* v2L = reinterpret_cast<float*>(lds + 16384);    // 16KB
    int*   i1L = reinterpret_cast<int*>(lds + 32768);      // 16KB
    int*   kidxL = reinterpret_cast<int*>(lds + 49152);    // 512B
#pragma unroll
    for (int ti = 0; ti < 4; ++ti)
#pragma unroll
        for (int rr = 0; rr < 4; ++rr) {
            int t_local = wr * 64 + ti * 16 + quad * 4 + rr;
            int slot = t_local * 32 + wc * 16 + l15;
            v1L[slot] = v1[ti * 4 + rr];
            v2L[slot] = v2[ti * 4 + rr];
            i1L[slot] = i1[ti * 4 + rr];
        }
    __syncthreads();

    if (tid < 128) {
        int base = tid * 32;
        float V1 = v1L[base], V2 = v2L[base];
        int I = i1L[base];
        for (int j = 1; j < 32; ++j) {
            float b1 = v1L[base + j];
            float b2 = v2L[base + j];
            int bi = i1L[base + j];
            if (b1 < V1 || (b1 == V1 && bi < I)) { V2 = fminf(V1, b2); V1 = b1; I = bi; }
            else V2 = fminf(V2, b1);
        }
        idx[tok0 + tid] = I;
        kidxL[tid] = I;
        if (V2 - V1 < MARGIN) {
            int p = atomicAdd(flagcnt, 1);
            flaglist[p] = tok0 + tid;
        }
    }
    __syncthreads();

    // ---- phase 2a: hist atomics (early, latency overlaps stores)
    if (tid < 128) atomicAdd(&hist[kidxL[tid]], 1);

    // ---- phase 2b: enc rows — 128 x 4KB, 2KB contiguous per instruction
    {
        float2* ebase = reinterpret_cast<float2*>(enc + ((size_t)tok0 << 10));
        const int f0 = tid * 2;
        const int f1 = (tid + 256) * 2;
        for (int t = 0; t < 128; ++t) {
            int k = kidxL[t];
            float2 z0, z1;
            z0.x = (f0 == k)     ? 1.0f : 0.0f;
            z0.y = (f0 + 1 == k) ? 1.0f : 0.0f;
            z1.x = (f1 == k)     ? 1.0f : 0.0f;
            z1.y = (f1 + 1 == k) ? 1.0f : 0.0f;
            ebase[(size_t)t * 512 + tid]       = z0;
            ebase[(size_t)t * 512 + tid + 256] = z1;
        }
    }

    // ---- phase 2c: quant rows + f64 loss partial (x re-read, L2-warm)
    double lacc = 0.0;
    {
        const int c2 = (tid & 63) * 2;           // float offset within row
        const int tsub = tid >> 6;               // token sub-index 0..3
        for (int it = 0; it < 32; ++it) {
            int t = it * 4 + tsub;
            int k = kidxL[t];
            size_t go = (((size_t)(tok0 + t)) << 7) + c2;
            float2 xv = *reinterpret_cast<const float2*>(xg + go);
            float2 ev = *reinterpret_cast<const float2*>(emb + (((size_t)k) << 7) + c2);
            float dx = ev.x - xv.x;
            float dy = ev.y - xv.y;
            float2 q; q.x = xv.x + dx; q.y = xv.y + dy;
            *reinterpret_cast<float2*>(quant + go) = q;
            lacc += (double)(dx * dx) + (double)(dy * dy);
        }
    }
    for (int off = 32; off > 0; off >>= 1) lacc += __shfl_down(lacc, off);
    double* wsum = reinterpret_cast<double*>(lds + 49664);
    if (lane == 0) wsum[w] = lacc;
    __syncthreads();
    if (tid == 0) part[blockIdx.x] = wsum[0] + wsum[1] + wsum[2] + wsum[3];
}

// ---------------------------------------------------------------------------
// fp64 rescan of near-tie tokens; patches outputs only when idx changes.
// ---------------------------------------------------------------------------
__global__ __launch_bounds__(256) void k_refine(const float* __restrict__ xg,
                                                const float* __restrict__ emb,
                                                const double* __restrict__ se64,
                                                const int* __restrict__ flaglist,
                                                const int* __restrict__ flagcnt,
                                                int* __restrict__ idx,
                                                float* __restrict__ quant,
                                                float* __restrict__ enc,
                                                int* __restrict__ hist,
                                                double* __restrict__ lossx) {
    __shared__ float xsh[DIM];
    __shared__ double rv[256];
    __shared__ int ri[256];
    const int tid = threadIdx.x;
    const int cnt = *flagcnt;

    for (int f = blockIdx.x; f < cnt; f += gridDim.x) {
        int t = flaglist[f];
        __syncthreads();
        if (tid < DIM) xsh[tid] = xg[(size_t)t * DIM + tid];
        __syncthreads();

        double best = 1.0e300;
        int bi = 0;
#pragma unroll
        for (int j = 0; j < 4; ++j) {
            int k = tid * 4 + j;
            const float* er = emb + (size_t)k * DIM;
            double m = 0.0;
            for (int d = 0; d < DIM; ++d)
                m = fma((double)xsh[d], (double)er[d], m);
            double u = se64[k] - 2.0 * m;
            if (u < best) { best = u; bi = k; }
        }
        rv[tid] = best;
        ri[tid] = bi;
        __syncthreads();
        for (int s = 128; s > 0; s >>= 1) {
            if (tid < s) {
                if (rv[tid + s] < rv[tid] ||
                    (rv[tid + s] == rv[tid] && ri[tid + s] < ri[tid])) {
                    rv[tid] = rv[tid + s];
                    ri[tid] = ri[tid + s];
                }
            }
            __syncthreads();
        }
        int newk = ri[0];
        int oldk = idx[t];
        if (newk != oldk) {
            // patch quant row + loss delta (bit-identical recompute of old term)
            double delta = 0.0;
            if (tid < DIM) {
                float xd = xsh[tid];
                float en = emb[((size_t)newk << 7) + tid];
                float eo = emb[((size_t)oldk << 7) + tid];
                float dn = en - xd;
                float dl = eo - xd;
                quant[((size_t)t << 7) + tid] = xd + dn;
                delta = (double)(dn * dn) - (double)(dl * dl);
            }
            rv[tid] = delta;
            __syncthreads();
            for (int s = 128; s > 0; s >>= 1) {
                if (tid < s) rv[tid] += rv[tid + s];
                __syncthreads();
            }
            if (tid == 0) {
                atomicAdd(lossx, rv[0]);
                enc[((size_t)t << 10) + oldk] = 0.0f;
                enc[((size_t)t << 10) + newk] = 1.0f;
                atomicAdd(&hist[oldk], -1);
                atomicAdd(&hist[newk], 1);
                idx[t] = newk;
            }
        }
        __syncthreads();
    }
}

// ---------------------------------------------------------------------------
__global__ __launch_bounds__(256) void k_final(const double* __restrict__ part,
                                               const double* __restrict__ lossx,
                                               const int* __restrict__ hist,
                                               float* __restrict__ out_loss,
                                               float* __restrict__ out_perp) {
    __shared__ double red[256];
    const int tid = threadIdx.x;

    double s = 0.0;
    for (int i = tid; i < 512; i += 256) s += part[i];
    red[tid] = s;
    __syncthreads();
    for (int st = 128; st > 0; st >>= 1) {
        if (tid < st) red[tid] += red[tid + st];
        __syncthreads();
    }
    double loss = (red[0] + *lossx) / 8388608.0;
    __syncthreads();

    double e = 0.0;
    for (int b = tid; b < KCODE; b += 256) {
        double p = (double)hist[b] * (1.0 / 65536.0);
        e += p * log(p + 1e-10);
    }
    red[tid] = e;
    __syncthreads();
    for (int st = 128; st > 0; st >>= 1) {
        if (tid < st) red[tid] += red[tid + st];
        __syncthreads();
    }
    if (tid == 0) {
        *out_loss = (float)loss;
        *out_perp = (float)exp(-red[0]);
    }
}

// ---------------------------------------------------------------------------
extern "C" void kernel_launch(void* const* d_in, const int* in_sizes, int n_in,
                              void* d_out, int out_size, void* d_ws, size_t ws_size,
                              hipStream_t stream) {
    const float* x   = (const float*)d_in[0];
    const float* emb = (const float*)d_in[1];
    float* out = (float*)d_out;
    char*  ws  = (char*)d_ws;

    double* se64   = (double*)(ws + WS_SE64);
    float*  se32   = (float*)(ws + WS_SE32);
    int*    idx    = (int*)(ws + WS_IDX);
    int*    flglst = (int*)(ws + WS_FLAGLIST);
    int*    flgcnt = (int*)(ws + WS_FLAGCNT);
    double* lossx  = (double*)(ws + WS_LOSSX);
    int*    hist   = (int*)(ws + WS_HIST);
    double* part   = (double*)(ws + WS_PART);
    unsigned short* Ep = (unsigned short*)(ws + WS_EP);

    float* quant = out + OUT_QUANT_OFF;
    float* enc   = out + OUT_ENC_OFF;

    // zero flagcnt + lossx + hist
    hipMemsetAsync(ws + WS_FLAGCNT, 0, WS_PART - WS_FLAGCNT, stream);

    k_code <<<KCODE / 8, 256, 0, stream>>>(emb, se64, se32, Ep);
    k_main <<<N_TOK / 128, 256, 0, stream>>>(x, emb, Ep, se32, idx, flglst, flgcnt,
                                             quant, enc, part, hist);
    k_refine<<<256, 256, 0, stream>>>(x, emb, se64, flglst, flgcnt, idx,
                                      quant, enc, hist, lossx);
    k_final<<<1, 256, 0, stream>>>(part, lossx, hist, out, out + OUT_PERP_OFF);
}